// Round 1
// baseline (202.332 us; speedup 1.0000x reference)
//
#include <hip/hip_runtime.h>
#include <math.h>

typedef __bf16 b16x8 __attribute__((ext_vector_type(8)));
typedef float  f32x4 __attribute__((ext_vector_type(4)));

#define B_    8
#define CIN_  64
#define COUT_ 64
#define Hs    96
#define Ws    96
#define PLANE (Hs*Ws)        // 9216
#define IMG   (CIN_*PLANE)   // 589824
#define NP    (B_*PLANE)     // 73728
#define NBLK  (NP/64)        // 1152

__device__ __forceinline__ int swz(int bid) { return (bid & 7) * (NBLK / 8) + (bid >> 3); }

// Fused: blocks [0,288) transpose x -> channel-last bf16 xT;
//        blocks [288,432) repack weights into per-lane MFMA A-fragment order.
// Independent work, fused to save one launch and overlap the tiny repack.
__global__ void prep_xpose(const float* __restrict__ x,
                           const float* __restrict__ weight, const float* __restrict__ w_off,
                           __bf16* __restrict__ xT,
                           __bf16* __restrict__ wAB, __bf16* __restrict__ wAO) {
    int bid = blockIdx.x;
    if (bid < 288) {
        // x [b][c][y][x] fp32 -> xT [b][y][x][c] bf16 (channel-last).
        int p = bid * 256 + threadIdx.x;
        int b = p / PLANE, r = p - b * PLANE;
        const float* src = x + b * IMG + r;
        __bf16 buf[64];
#pragma unroll
        for (int c = 0; c < 64; ++c) buf[c] = (__bf16)src[c * PLANE];
        b16x8* dst = (b16x8*)(xT + (size_t)p * 64);
#pragma unroll
        for (int j = 0; j < 8; ++j) dst[j] = ((const b16x8*)buf)[j];
    } else {
        int i = (bid - 288) * 256 + threadIdx.x;
        if (i < 36864) {
            int e = i & 7, lane = (i >> 3) & 63, mt = (i >> 9) & 3, ks = (i >> 11) & 1, k = i >> 12;
            int o = mt * 16 + (lane & 15);
            int c = ks * 32 + ((lane >> 4) << 3) + e;
            wAB[i] = (__bf16)weight[o * 576 + c * 9 + k];
        }
        if (i < 18432) {
            int e = i & 7, lane = (i >> 3) & 63, mt = (i >> 9) & 1, ks = (i >> 10) & 1, t = i >> 11;
            int ch = mt * 16 + (lane & 15);
            int c  = ks * 32 + ((lane >> 4) << 3) + e;
            wAO[i] = (ch < 27) ? (__bf16)w_off[ch * 576 + c * 9 + t] : (__bf16)(0.f);
        }
    }
}

// Barrier-free, channel-last: one b128 load = one 8-channel fragment octet.
// Per tap phase B: 4 positions x 2 octets = 8 b128 loads. Phase A: 2 loads +
// cndmask per tap. Half-tap software pipeline as before.
// launch_bounds(256, 8): VGPR=60 <= 64, so HW supports 8 waves/SIMD; the old
// (256,3) capped residency at 3 blocks/CU and forced a 2-round dispatch tail
// (grid = 4.5 blocks/CU) -> measured 30% occupancy while latency-bound.
// With the cap lifted the whole 1152-block grid is resident in one round.
__global__ __launch_bounds__(256, 8)
void deform_mfma(const __bf16* __restrict__ xT,
                 const __bf16* __restrict__ wAO,
                 const float* __restrict__ b_off,
                 const __bf16* __restrict__ wAB,
                 const float* __restrict__ bias,
                 float* __restrict__ out) {
    __shared__ float omL[4][27 * 16];   // 6912 B, wave-private

    int tid  = threadIdx.x;
    int lane = tid & 63;
    int g    = __builtin_amdgcn_readfirstlane(tid >> 6);
    int n    = lane & 15;    // pixel within strip / MFMA col
    int q    = lane >> 4;    // octet: this lane owns channels q*8..q*8+7 (ks0) / +32 (ks1)

    int pg0  = swz(blockIdx.x) * 64;
    int b    = pg0 / PLANE;
    int rblk = pg0 - b * PLANE;
    int rr   = rblk + g * 16 + n;
    int h    = rr / Ws, w = rr - h * Ws;
    const __bf16* xTb = xT + (size_t)b * PLANE * 64 + q * 8;   // +octet offset

    float* omW = &omL[g][0];
    const b16x8* wAOv = (const b16x8*)wAO;
    const b16x8* wABv = (const b16x8*)wAB;

    // ---------------- Phase A: offset conv via MFMA ----------------
    f32x4 accA0 = {0.f, 0.f, 0.f, 0.f};
    f32x4 accA1 = {0.f, 0.f, 0.f, 0.f};

    auto posA = [&](int t, bool* mk) -> const b16x8* {
        int ky = t / 3, kx = t - ky * 3;
        int yy = h - 1 + ky, xx = w - 1 + kx;
        *mk = (yy >= 0 && yy < Hs && xx >= 0 && xx < Ws);
        return (const b16x8*)(xTb + (min(max(yy, 0), Hs - 1) * Ws + min(max(xx, 0), Ws - 1)) * 64);
    };

    bool mkC;
    const b16x8* pC = posA(0, &mkC);
    b16x8 eC = pC[0], oC = pC[4];   // octet q (ks0) and octet q+32ch (ks1)
    const b16x8 ZER = {};

#pragma unroll 1
    for (int t = 0; t < 9; ++t) {
        b16x8 af0 = wAOv[((t * 2 + 0) * 2 + 0) * 64 + lane];
        b16x8 af1 = wAOv[((t * 2 + 0) * 2 + 1) * 64 + lane];
        b16x8 af2 = wAOv[((t * 2 + 1) * 2 + 0) * 64 + lane];
        b16x8 af3 = wAOv[((t * 2 + 1) * 2 + 1) * 64 + lane];

        b16x8 bf0 = mkC ? eC : ZER;
        b16x8 bf1 = mkC ? oC : ZER;

        if (t < 8) {   // prefetch next tap (covered by 4 MFMAs below)
            pC = posA(t + 1, &mkC);
            eC = pC[0]; oC = pC[4];
        }

        accA0 = __builtin_amdgcn_mfma_f32_16x16x32_bf16(af0, bf0, accA0, 0, 0, 0);
        accA1 = __builtin_amdgcn_mfma_f32_16x16x32_bf16(af1, bf0, accA1, 0, 0, 0);
        accA0 = __builtin_amdgcn_mfma_f32_16x16x32_bf16(af2, bf1, accA0, 0, 0, 0);
        accA1 = __builtin_amdgcn_mfma_f32_16x16x32_bf16(af3, bf1, accA1, 0, 0, 0);
    }
#pragma unroll
    for (int rg = 0; rg < 4; ++rg) { int ch = q * 4 + rg;      omW[ch * 16 + n] = accA0[rg] + b_off[ch]; }
#pragma unroll
    for (int rg = 0; rg < 4; ++rg) { int ch = 16 + q * 4 + rg; if (ch < 27) omW[ch * 16 + n] = accA1[rg] + b_off[ch]; }

    // ---------------- Phase B: sampling + main conv ----------------
    f32x4 acc0 = {0.f, 0.f, 0.f, 0.f};
    f32x4 acc1 = {0.f, 0.f, 0.f, 0.f};
    f32x4 acc2 = {0.f, 0.f, 0.f, 0.f};
    f32x4 acc3 = {0.f, 0.f, 0.f, 0.f};

    const b16x8 *P00, *P01, *P10, *P11;   // current tap position pointers (octet base)
    float W00, W01, W10, W11;             // current tap bilinear weights (mask folded)

#define CALC_FROM(dy, dx, mo, kk) do {                                            \
        float m  = 1.f / (1.f + __expf(-(mo)));                                   \
        int ky = (kk) / 3, kx = (kk) - ky * 3;                                    \
        float ys = (float)(h - 1 + ky) + (dy);                                    \
        float xs = (float)(w - 1 + kx) + (dx);                                    \
        float y0f = floorf(ys), x0f = floorf(xs);                                 \
        float ly = ys - y0f, lx = xs - x0f;                                       \
        float hy = 1.f - ly, hx = 1.f - lx;                                       \
        int y0 = (int)y0f, x0 = (int)x0f, y1 = y0 + 1, x1 = x0 + 1;               \
        bool vy0 = (y0 >= 0) && (y0 < Hs), vy1 = (y1 >= 0) && (y1 < Hs);          \
        bool vx0 = (x0 >= 0) && (x0 < Ws), vx1 = (x1 >= 0) && (x1 < Ws);          \
        W00 = (vy0 && vx0) ? m * hy * hx : 0.f;                                   \
        W01 = (vy0 && vx1) ? m * hy * lx : 0.f;                                   \
        W10 = (vy1 && vx0) ? m * ly * hx : 0.f;                                   \
        W11 = (vy1 && vx1) ? m * ly * lx : 0.f;                                   \
        int y0c = min(max(y0, 0), Hs - 1), y1c = min(max(y1, 0), Hs - 1);         \
        int x0c = min(max(x0, 0), Ws - 1), x1c = min(max(x1, 0), Ws - 1);         \
        P00 = (const b16x8*)(xTb + (y0c * Ws + x0c) * 64);                        \
        P01 = (const b16x8*)(xTb + (y0c * Ws + x1c) * 64);                        \
        P10 = (const b16x8*)(xTb + (y1c * Ws + x0c) * 64);                        \
        P11 = (const b16x8*)(xTb + (y1c * Ws + x1c) * 64);                        \
    } while (0)

    {
        float dy0 = omW[0 * 16 + n], dx0 = omW[1 * 16 + n], mo0 = omW[18 * 16 + n];
        CALC_FROM(dy0, dx0, mo0, 0);
    }
    b16x8 e00 = P00[0], e01 = P01[0], e10 = P10[0], e11 = P11[0];   // ks0 octets

#pragma unroll 1
    for (int k = 0; k < 9; ++k) {
        b16x8 a0 = wABv[(k * 8 + 0) * 64 + lane];
        b16x8 a1 = wABv[(k * 8 + 1) * 64 + lane];
        b16x8 a2 = wABv[(k * 8 + 2) * 64 + lane];
        b16x8 a3 = wABv[(k * 8 + 3) * 64 + lane];
        // ks1 octets (channels +32) for this tap
        b16x8 o00 = P00[4], o01 = P01[4], o10 = P10[4], o11 = P11[4];

        // prefetch next tap's om triple (LDS; latency hidden behind combine+MFMA)
        int kn = (k < 8) ? (k + 1) : 8;
        float dyN = omW[(2 * kn) * 16 + n];
        float dxN = omW[(2 * kn + 1) * 16 + n];
        float moN = omW[(18 + kn) * 16 + n];

        float V00 = W00, V01 = W01, V10 = W10, V11 = W11;   // save for ks1 combine

        b16x8 fe;
#pragma unroll
        for (int j = 0; j < 8; ++j)
            fe[j] = (__bf16)((float)e00[j] * W00 + (float)e01[j] * W01 +
                             (float)e10[j] * W10 + (float)e11[j] * W11);
        acc0 = __builtin_amdgcn_mfma_f32_16x16x32_bf16(a0, fe, acc0, 0, 0, 0);
        acc1 = __builtin_amdgcn_mfma_f32_16x16x32_bf16(a1, fe, acc1, 0, 0, 0);
        acc2 = __builtin_amdgcn_mfma_f32_16x16x32_bf16(a2, fe, acc2, 0, 0, 0);
        acc3 = __builtin_amdgcn_mfma_f32_16x16x32_bf16(a3, fe, acc3, 0, 0, 0);

        b16x8 a4 = wABv[(k * 8 + 4) * 64 + lane];
        b16x8 a5 = wABv[(k * 8 + 5) * 64 + lane];
        b16x8 a6 = wABv[(k * 8 + 6) * 64 + lane];
        b16x8 a7 = wABv[(k * 8 + 7) * 64 + lane];

        if (k < 8) {   // CALC(k+1) + issue its ks0 octets; covered by combine+MFMAs
            CALC_FROM(dyN, dxN, moN, k + 1);
            e00 = P00[0]; e01 = P01[0]; e10 = P10[0]; e11 = P11[0];
        }

        b16x8 fo;
#pragma unroll
        for (int j = 0; j < 8; ++j)
            fo[j] = (__bf16)((float)o00[j] * V00 + (float)o01[j] * V01 +
                             (float)o10[j] * V10 + (float)o11[j] * V11);
        acc0 = __builtin_amdgcn_mfma_f32_16x16x32_bf16(a4, fo, acc0, 0, 0, 0);
        acc1 = __builtin_amdgcn_mfma_f32_16x16x32_bf16(a5, fo, acc1, 0, 0, 0);
        acc2 = __builtin_amdgcn_mfma_f32_16x16x32_bf16(a6, fo, acc2, 0, 0, 0);
        acc3 = __builtin_amdgcn_mfma_f32_16x16x32_bf16(a7, fo, acc3, 0, 0, 0);
    }
#undef CALC_FROM

    // epilogue: C layout row=(q*4+rg) within m-tile, col=n -> pixel rr
    int ob = b * (COUT_ * PLANE) + rblk + g * 16 + n;
    f32x4 bs0 = *(const f32x4*)&bias[q * 4];
    f32x4 bs1 = *(const f32x4*)&bias[16 + q * 4];
    f32x4 bs2 = *(const f32x4*)&bias[32 + q * 4];
    f32x4 bs3 = *(const f32x4*)&bias[48 + q * 4];
#pragma unroll
    for (int rg = 0; rg < 4; ++rg) { int o =      q * 4 + rg; out[ob + o * PLANE] = acc0[rg] + bs0[rg]; }
#pragma unroll
    for (int rg = 0; rg < 4; ++rg) { int o = 16 + q * 4 + rg; out[ob + o * PLANE] = acc1[rg] + bs1[rg]; }
#pragma unroll
    for (int rg = 0; rg < 4; ++rg) { int o = 32 + q * 4 + rg; out[ob + o * PLANE] = acc2[rg] + bs2[rg]; }
#pragma unroll
    for (int rg = 0; rg < 4; ++rg) { int o = 48 + q * 4 + rg; out[ob + o * PLANE] = acc3[rg] + bs3[rg]; }
}

extern "C" void kernel_launch(void* const* d_in, const int* in_sizes, int n_in,
                              void* d_out, int out_size, void* d_ws, size_t ws_size,
                              hipStream_t stream) {
    const float* x      = (const float*)d_in[0];
    const float* w_off  = (const float*)d_in[1];
    const float* b_off  = (const float*)d_in[2];
    const float* weight = (const float*)d_in[3];
    const float* bias   = (const float*)d_in[4];
    float* out = (float*)d_out;

    char* ws = (char*)d_ws;
    __bf16* wAB = (__bf16*)ws;               //  73728 B
    __bf16* wAO = (__bf16*)(ws + 73728);     //  36864 B
    __bf16* xT  = (__bf16*)(ws + 131072);    // 9437184 B (bf16 channel-last)

    prep_xpose<<<432, 256, 0, stream>>>(x, weight, w_off, xT, wAB, wAO);
    deform_mfma<<<NBLK, 256, 0, stream>>>(xT, wAO, b_off, wAB, bias, out);
}

// Round 2
// 143.026 us; speedup vs baseline: 1.4147x; 1.4147x over previous
//
#include <hip/hip_runtime.h>
#include <math.h>

typedef __bf16 b16x8 __attribute__((ext_vector_type(8)));
typedef float  f32x4 __attribute__((ext_vector_type(4)));

#define B_    8
#define CIN_  64
#define COUT_ 64
#define Hs    96
#define Ws    96
#define PLANE (Hs*Ws)        // 9216
#define IMG   (CIN_*PLANE)   // 589824
#define NP    (B_*PLANE)     // 73728
#define NBLK  (NP/32)        // 2304 blocks, 32 pixels each (K-split doubles waves)

__device__ __forceinline__ int swz(int bid) { return (bid & 7) * (NBLK / 8) + (bid >> 3); }

// Fused: blocks [0,288) transpose x -> channel-last bf16 xT;
//        blocks [288,432) repack weights into per-lane MFMA A-fragment order.
__global__ void prep_xpose(const float* __restrict__ x,
                           const float* __restrict__ weight, const float* __restrict__ w_off,
                           __bf16* __restrict__ xT,
                           __bf16* __restrict__ wAB, __bf16* __restrict__ wAO) {
    int bid = blockIdx.x;
    if (bid < 288) {
        // x [b][c][y][x] fp32 -> xT [b][y][x][c] bf16 (channel-last).
        int p = bid * 256 + threadIdx.x;
        int b = p / PLANE, r = p - b * PLANE;
        const float* src = x + b * IMG + r;
        __bf16 buf[64];
#pragma unroll
        for (int c = 0; c < 64; ++c) buf[c] = (__bf16)src[c * PLANE];
        b16x8* dst = (b16x8*)(xT + (size_t)p * 64);
#pragma unroll
        for (int j = 0; j < 8; ++j) dst[j] = ((const b16x8*)buf)[j];
    } else {
        int i = (bid - 288) * 256 + threadIdx.x;
        if (i < 36864) {
            int e = i & 7, lane = (i >> 3) & 63, mt = (i >> 9) & 3, ks = (i >> 11) & 1, k = i >> 12;
            int o = mt * 16 + (lane & 15);
            int c = ks * 32 + ((lane >> 4) << 3) + e;
            wAB[i] = (__bf16)weight[o * 576 + c * 9 + k];
        }
        if (i < 18432) {
            int e = i & 7, lane = (i >> 3) & 63, mt = (i >> 9) & 1, ks = (i >> 10) & 1, t = i >> 11;
            int ch = mt * 16 + (lane & 15);
            int c  = ks * 32 + ((lane >> 4) << 3) + e;
            wAO[i] = (ch < 27) ? (__bf16)w_off[ch * 576 + c * 9 + t] : (__bf16)(0.f);
        }
    }
}

// K-split deform conv:
//   block = 256 threads = 4 waves = 2 pixel-strips (s) x 2 K-halves (kh).
//   Wave (s,kh): 16 pixels, input channels kh*32..kh*32+31 only.
//   -> per tap: 4 gather loads (was 8), 4 MFMAs (was 8); 2x total waves
//      (9216 vs 4608) so ~24-28 resident waves/CU vs 18 before.
//   Phase A partial om summed via LDS at read time; epilogue exchanges the
//   accumulator half each wave does not store (one LDS round trip).
// launch_bounds(256,6): VGPR cap 85 -- room for the pipelined live set
// (round-1 lesson: an 8-wave cap forced spill, 390 MB scratch traffic).
__global__ __launch_bounds__(256, 6)
void deform_mfma(const __bf16* __restrict__ xT,
                 const __bf16* __restrict__ wAO,
                 const float* __restrict__ b_off,
                 const __bf16* __restrict__ wAB,
                 const float* __restrict__ bias,
                 float* __restrict__ out) {
    __shared__ float omP[2][2][28][16];   // [strip][khalf][ch][n]  7168 B
    __shared__ float xch[2][2][64][8];    // [strip][slot][lane][e] 8192 B

    int tid  = threadIdx.x;
    int lane = tid & 63;
    int g    = __builtin_amdgcn_readfirstlane(tid >> 6);
    int s    = g & 1;        // pixel strip within block
    int kh   = g >> 1;       // K-half: input channels kh*32..kh*32+31
    int n    = lane & 15;    // pixel within strip / MFMA col
    int q    = lane >> 4;    // octet: channels kh*32 + q*8 .. +7

    int pg0  = swz(blockIdx.x) * 32;
    int b    = pg0 / PLANE;
    int rblk = pg0 - b * PLANE;
    int rr   = rblk + s * 16 + n;
    int h    = rr / Ws, w = rr - h * Ws;
    const __bf16* xTb = xT + (size_t)b * PLANE * 64 + kh * 32 + q * 8;

    const b16x8* wAOv = (const b16x8*)wAO;
    const b16x8* wABv = (const b16x8*)wAB;

    // ---------------- Phase A: offset conv via MFMA (K-half partial) --------
    f32x4 accA0 = {0.f, 0.f, 0.f, 0.f};
    f32x4 accA1 = {0.f, 0.f, 0.f, 0.f};

    auto posA = [&](int t, bool* mk) -> const b16x8* {
        int ky = t / 3, kx = t - ky * 3;
        int yy = h - 1 + ky, xx = w - 1 + kx;
        *mk = (yy >= 0 && yy < Hs && xx >= 0 && xx < Ws);
        return (const b16x8*)(xTb + (min(max(yy, 0), Hs - 1) * Ws + min(max(xx, 0), Ws - 1)) * 64);
    };

    bool mkC;
    const b16x8* pC = posA(0, &mkC);
    b16x8 eC = pC[0];
    const b16x8 ZER = {};

#pragma unroll 1
    for (int t = 0; t < 9; ++t) {
        b16x8 af0 = wAOv[((t * 2 + kh) * 2 + 0) * 64 + lane];
        b16x8 af1 = wAOv[((t * 2 + kh) * 2 + 1) * 64 + lane];
        b16x8 bf  = mkC ? eC : ZER;
        if (t < 8) { pC = posA(t + 1, &mkC); eC = pC[0]; }
        accA0 = __builtin_amdgcn_mfma_f32_16x16x32_bf16(af0, bf, accA0, 0, 0, 0);
        accA1 = __builtin_amdgcn_mfma_f32_16x16x32_bf16(af1, bf, accA1, 0, 0, 0);
    }
    // write K-half partials (b_off folded into kh=0 partial)
#pragma unroll
    for (int rg = 0; rg < 4; ++rg) {
        int ch = q * 4 + rg;
        omP[s][kh][ch][n] = accA0[rg] + (kh ? 0.f : b_off[ch]);
    }
#pragma unroll
    for (int rg = 0; rg < 4; ++rg) {
        int ch = 16 + q * 4 + rg;
        if (ch < 27) omP[s][kh][ch][n] = accA1[rg] + (kh ? 0.f : b_off[ch]);
    }
    __syncthreads();

    // ---------------- Phase B: sampling + main conv (K-half partial) --------
    f32x4 acc0 = {0.f, 0.f, 0.f, 0.f};
    f32x4 acc1 = {0.f, 0.f, 0.f, 0.f};
    f32x4 acc2 = {0.f, 0.f, 0.f, 0.f};
    f32x4 acc3 = {0.f, 0.f, 0.f, 0.f};

    const float* om0 = &omP[s][0][0][0];
    const float* om1 = &omP[s][1][0][0];

    const b16x8 *P00, *P01, *P10, *P11;
    float W00, W01, W10, W11;

#define CALC_FROM(dy, dx, mo, kk) do {                                            \
        float m  = 1.f / (1.f + __expf(-(mo)));                                   \
        int ky = (kk) / 3, kx = (kk) - ky * 3;                                    \
        float ys = (float)(h - 1 + ky) + (dy);                                    \
        float xs = (float)(w - 1 + kx) + (dx);                                    \
        float y0f = floorf(ys), x0f = floorf(xs);                                 \
        float ly = ys - y0f, lx = xs - x0f;                                       \
        float hy = 1.f - ly, hx = 1.f - lx;                                       \
        int y0 = (int)y0f, x0 = (int)x0f, y1 = y0 + 1, x1 = x0 + 1;               \
        bool vy0 = (y0 >= 0) && (y0 < Hs), vy1 = (y1 >= 0) && (y1 < Hs);          \
        bool vx0 = (x0 >= 0) && (x0 < Ws), vx1 = (x1 >= 0) && (x1 < Ws);          \
        W00 = (vy0 && vx0) ? m * hy * hx : 0.f;                                   \
        W01 = (vy0 && vx1) ? m * hy * lx : 0.f;                                   \
        W10 = (vy1 && vx0) ? m * ly * hx : 0.f;                                   \
        W11 = (vy1 && vx1) ? m * ly * lx : 0.f;                                   \
        int y0c = min(max(y0, 0), Hs - 1), y1c = min(max(y1, 0), Hs - 1);         \
        int x0c = min(max(x0, 0), Ws - 1), x1c = min(max(x1, 0), Ws - 1);         \
        P00 = (const b16x8*)(xTb + (y0c * Ws + x0c) * 64);                        \
        P01 = (const b16x8*)(xTb + (y0c * Ws + x1c) * 64);                        \
        P10 = (const b16x8*)(xTb + (y1c * Ws + x0c) * 64);                        \
        P11 = (const b16x8*)(xTb + (y1c * Ws + x1c) * 64);                        \
    } while (0)

    {
        float dy0 = om0[0 * 16 + n] + om1[0 * 16 + n];
        float dx0 = om0[1 * 16 + n] + om1[1 * 16 + n];
        float mo0 = om0[18 * 16 + n] + om1[18 * 16 + n];
        CALC_FROM(dy0, dx0, mo0, 0);
    }
    b16x8 e00 = P00[0], e01 = P01[0], e10 = P10[0], e11 = P11[0];

#pragma unroll 1
    for (int k = 0; k < 9; ++k) {
        b16x8 a0 = wABv[(k * 8 + kh * 4 + 0) * 64 + lane];
        b16x8 a1 = wABv[(k * 8 + kh * 4 + 1) * 64 + lane];
        b16x8 a2 = wABv[(k * 8 + kh * 4 + 2) * 64 + lane];
        b16x8 a3 = wABv[(k * 8 + kh * 4 + 3) * 64 + lane];

        // next tap's om triple (LDS; latency hidden behind combine+MFMA)
        int kn = (k < 8) ? (k + 1) : 8;
        float dyN = om0[(2 * kn) * 16 + n]     + om1[(2 * kn) * 16 + n];
        float dxN = om0[(2 * kn + 1) * 16 + n] + om1[(2 * kn + 1) * 16 + n];
        float moN = om0[(18 + kn) * 16 + n]    + om1[(18 + kn) * 16 + n];

        b16x8 fe;
#pragma unroll
        for (int j = 0; j < 8; ++j)
            fe[j] = (__bf16)((float)e00[j] * W00 + (float)e01[j] * W01 +
                             (float)e10[j] * W10 + (float)e11[j] * W11);

        acc0 = __builtin_amdgcn_mfma_f32_16x16x32_bf16(a0, fe, acc0, 0, 0, 0);
        acc1 = __builtin_amdgcn_mfma_f32_16x16x32_bf16(a1, fe, acc1, 0, 0, 0);

        if (k < 8) {   // prefetch next tap's octets; covered by MFMAs below
            CALC_FROM(dyN, dxN, moN, k + 1);
            e00 = P00[0]; e01 = P01[0]; e10 = P10[0]; e11 = P11[0];
        }

        acc2 = __builtin_amdgcn_mfma_f32_16x16x32_bf16(a2, fe, acc2, 0, 0, 0);
        acc3 = __builtin_amdgcn_mfma_f32_16x16x32_bf16(a3, fe, acc3, 0, 0, 0);
    }
#undef CALC_FROM

    // ---------------- Epilogue: cross-K-half exchange + store ---------------
    // Wave kh writes the output half it does NOT store; reads partner's half.
    //   kh=0 stores channels  0..31 (tiles 0,1), gives away tiles 2,3
    //   kh=1 stores channels 32..63 (tiles 2,3), gives away tiles 0,1
    {
        f32x4* xw = (f32x4*)&xch[s][kh][lane][0];
        if (kh == 0) { xw[0] = acc2; xw[1] = acc3; }
        else         { xw[0] = acc0; xw[1] = acc1; }
    }
    __syncthreads();
    {
        const f32x4* xr = (const f32x4*)&xch[s][kh ^ 1][lane][0];
        f32x4 t0 = xr[0], t1 = xr[1];
        int ob = b * (COUT_ * PLANE) + rr;
        if (kh == 0) {
            f32x4 bs0 = *(const f32x4*)&bias[q * 4];
            f32x4 bs1 = *(const f32x4*)&bias[16 + q * 4];
#pragma unroll
            for (int rg = 0; rg < 4; ++rg) { int o =      q * 4 + rg; out[ob + o * PLANE] = acc0[rg] + t0[rg] + bs0[rg]; }
#pragma unroll
            for (int rg = 0; rg < 4; ++rg) { int o = 16 + q * 4 + rg; out[ob + o * PLANE] = acc1[rg] + t1[rg] + bs1[rg]; }
        } else {
            f32x4 bs2 = *(const f32x4*)&bias[32 + q * 4];
            f32x4 bs3 = *(const f32x4*)&bias[48 + q * 4];
#pragma unroll
            for (int rg = 0; rg < 4; ++rg) { int o = 32 + q * 4 + rg; out[ob + o * PLANE] = acc2[rg] + t0[rg] + bs2[rg]; }
#pragma unroll
            for (int rg = 0; rg < 4; ++rg) { int o = 48 + q * 4 + rg; out[ob + o * PLANE] = acc3[rg] + t1[rg] + bs3[rg]; }
        }
    }
}

extern "C" void kernel_launch(void* const* d_in, const int* in_sizes, int n_in,
                              void* d_out, int out_size, void* d_ws, size_t ws_size,
                              hipStream_t stream) {
    const float* x      = (const float*)d_in[0];
    const float* w_off  = (const float*)d_in[1];
    const float* b_off  = (const float*)d_in[2];
    const float* weight = (const float*)d_in[3];
    const float* bias   = (const float*)d_in[4];
    float* out = (float*)d_out;

    char* ws = (char*)d_ws;
    __bf16* wAB = (__bf16*)ws;               //  73728 B
    __bf16* wAO = (__bf16*)(ws + 73728);     //  36864 B
    __bf16* xT  = (__bf16*)(ws + 131072);    // 9437184 B (bf16 channel-last)

    prep_xpose<<<432, 256, 0, stream>>>(x, weight, w_off, xT, wAB, wAO);
    deform_mfma<<<NBLK, 256, 0, stream>>>(xT, wAO, b_off, wAB, bias, out);
}

// Round 3
// 118.061 us; speedup vs baseline: 1.7138x; 1.2115x over previous
//
#include <hip/hip_runtime.h>
#include <math.h>

typedef __bf16 b16x8 __attribute__((ext_vector_type(8)));
typedef float  f32x4 __attribute__((ext_vector_type(4)));

#define B_    8
#define CIN_  64
#define COUT_ 64
#define Hs    96
#define Ws    96
#define PLANE (Hs*Ws)        // 9216
#define IMG   (CIN_*PLANE)   // 589824
#define NP    (B_*PLANE)     // 73728
#define NBLK  (NP/32)        // 2304 blocks, 32 px each (row-aligned: 32 | 96)

// LDS window: rows h0-3..h0+3, cols c0-3..c0+36 (padded to 40)
#define WR 7
#define WC 40
#define WPIX (WR*WC)         // 280
#define WBYTES (WPIX*128)    // 35840 B

__device__ __forceinline__ int swz(int bid) { return (bid & 7) * (NBLK / 8) + (bid >> 3); }

// Fused: blocks [0,288) transpose x -> channel-last bf16 xT;
//        blocks [288,432) repack weights into per-lane MFMA A-fragment order.
__global__ void prep_xpose(const float* __restrict__ x,
                           const float* __restrict__ weight, const float* __restrict__ w_off,
                           __bf16* __restrict__ xT,
                           __bf16* __restrict__ wAB, __bf16* __restrict__ wAO) {
    int bid = blockIdx.x;
    if (bid < 288) {
        int p = bid * 256 + threadIdx.x;
        int b = p / PLANE, r = p - b * PLANE;
        const float* src = x + b * IMG + r;
        __bf16 buf[64];
#pragma unroll
        for (int c = 0; c < 64; ++c) buf[c] = (__bf16)src[c * PLANE];
        b16x8* dst = (b16x8*)(xT + (size_t)p * 64);
#pragma unroll
        for (int j = 0; j < 8; ++j) dst[j] = ((const b16x8*)buf)[j];
    } else {
        int i = (bid - 288) * 256 + threadIdx.x;
        if (i < 36864) {
            int e = i & 7, lane = (i >> 3) & 63, mt = (i >> 9) & 3, ks = (i >> 11) & 1, k = i >> 12;
            int o = mt * 16 + (lane & 15);
            int c = ks * 32 + ((lane >> 4) << 3) + e;
            wAB[i] = (__bf16)weight[o * 576 + c * 9 + k];
        }
        if (i < 18432) {
            int e = i & 7, lane = (i >> 3) & 63, mt = (i >> 9) & 1, ks = (i >> 10) & 1, t = i >> 11;
            int ch = mt * 16 + (lane & 15);
            int c  = ks * 32 + ((lane >> 4) << 3) + e;
            wAO[i] = (ch < 27) ? (__bf16)w_off[ch * 576 + c * 9 + t] : (__bf16)(0.f);
        }
    }
}

// R3: LDS-window deform conv. R0/R2 post-mortem: duration invariant (70.5 vs
// 70.9 us) under 1.6x occupancy and halved per-wave work => bound by divergent
// gather TRANSACTIONS (2 half-line touches per pixel-corner, ~6.6M line-touches
// chip-wide ~= 60 us of TA/TCP occupancy). Fix: stage the block's 7x40-pixel
// bf16 neighborhood into LDS ONCE (coalesced, full 128-B lines), sample from
// LDS (XOR-swizzled, <=2-way banks = free). Exact global fallback for samples
// outside the window (never taken for these offsets; exec-mask-skipped).
// LDS 43 KB -> 3 blocks/CU; launch_bounds(256,3) => ~168 VGPR budget (R1
// lesson: tight wave caps force spill).
__global__ __launch_bounds__(256, 3)
void deform_mfma(const __bf16* __restrict__ xT,
                 const __bf16* __restrict__ wAO,
                 const float* __restrict__ b_off,
                 const __bf16* __restrict__ wAB,
                 const float* __restrict__ bias,
                 float* __restrict__ out) {
    __shared__ __align__(16) unsigned char smemWin[WBYTES];   // window; aliased by epilogue xch
    __shared__ float omP[2][2][28][16];                        // [strip][khalf][ch][n] 7168 B

    int tid  = threadIdx.x;
    int lane = tid & 63;
    int g    = __builtin_amdgcn_readfirstlane(tid >> 6);
    int s    = g & 1;        // pixel strip within block
    int kh   = g >> 1;       // K-half: input channels kh*32..kh*32+31
    int n    = lane & 15;    // pixel within strip / MFMA col
    int q    = lane >> 4;    // octet: channels kh*32 + q*8 .. +7

    int pg0  = swz(blockIdx.x) * 32;
    int b    = pg0 / PLANE;
    int rblk = pg0 - b * PLANE;
    int h0   = rblk / Ws;          // whole block on one row (32 | 96)
    int c0   = rblk - h0 * Ws;
    int w    = c0 + s * 16 + n;
    const __bf16* xTimg = xT + (size_t)b * PLANE * 64;
    const __bf16* xTb   = xTimg + kh * 32 + q * 8;   // fallback gather base

    const b16x8* wAOv = (const b16x8*)wAO;
    const b16x8* wABv = (const b16x8*)wAB;
    int boff = kh * 64 + q * 16;   // this lane's byte offset within a pixel line

#define LDSRD(sl) (*(const b16x8*)(smemWin + (sl) * 128 + (boff ^ (((sl) & 7) << 4))))

    // ---------------- Stage window: 280 px * 128 B, coalesced ---------------
    // chunk idx: pix = idx>>3 (window slot), j = idx&7 (16-B chunk in line).
    // Write swizzled: byte ^= (slot&7)<<4 so phase-B reads (16 lanes, distinct
    // slots, same boff) spread across 8 bank groups (2-way = free).
#pragma unroll
    for (int r2 = 0; r2 < 9; ++r2) {
        int idx = tid + r2 * 256;
        if (r2 < 8 || tid < (WPIX * 8 - 2048)) {
            int pix = idx >> 3, j = idx & 7;
            int yw = pix / WC, xw = pix - yw * WC;
            int ys = min(max(h0 - 3 + yw, 0), Hs - 1);
            int xs = min(max(c0 - 3 + xw, 0), Ws - 1);
            b16x8 v = *(const b16x8*)(xTimg + ((ys * Ws + xs) * 64) + j * 8);
            *(b16x8*)(smemWin + pix * 128 + ((j * 16) ^ ((pix & 7) << 4))) = v;
        }
    }
    __syncthreads();

    // ---------------- Phase A: offset conv via MFMA (K-half partial) --------
    // Taps sample (h0-1+ky, w-1+kx): always inside the window.
    f32x4 accA0 = {0.f, 0.f, 0.f, 0.f};
    f32x4 accA1 = {0.f, 0.f, 0.f, 0.f};
    const b16x8 ZER = {};

#pragma unroll 3
    for (int t = 0; t < 9; ++t) {
        int ky = t / 3, kx = t - ky * 3;
        int yy = h0 - 1 + ky, xx = w - 1 + kx;
        bool mk = (yy >= 0 && yy < Hs && xx >= 0 && xx < Ws);   // zero-pad conv
        int sl = (ky + 2) * WC + (s * 16 + n + kx + 2);
        b16x8 bf = LDSRD(sl);
        bf = mk ? bf : ZER;
        b16x8 af0 = wAOv[((t * 2 + kh) * 2 + 0) * 64 + lane];
        b16x8 af1 = wAOv[((t * 2 + kh) * 2 + 1) * 64 + lane];
        accA0 = __builtin_amdgcn_mfma_f32_16x16x32_bf16(af0, bf, accA0, 0, 0, 0);
        accA1 = __builtin_amdgcn_mfma_f32_16x16x32_bf16(af1, bf, accA1, 0, 0, 0);
    }
#pragma unroll
    for (int rg = 0; rg < 4; ++rg) {
        int ch = q * 4 + rg;
        omP[s][kh][ch][n] = accA0[rg] + (kh ? 0.f : b_off[ch]);
    }
#pragma unroll
    for (int rg = 0; rg < 4; ++rg) {
        int ch = 16 + q * 4 + rg;
        if (ch < 27) omP[s][kh][ch][n] = accA1[rg] + (kh ? 0.f : b_off[ch]);
    }
    __syncthreads();

    // ---------------- Phase B: sampling (from LDS) + main conv --------------
    f32x4 acc0 = {0.f, 0.f, 0.f, 0.f};
    f32x4 acc1 = {0.f, 0.f, 0.f, 0.f};
    f32x4 acc2 = {0.f, 0.f, 0.f, 0.f};
    f32x4 acc3 = {0.f, 0.f, 0.f, 0.f};

    const float* om0 = &omP[s][0][0][0];
    const float* om1 = &omP[s][1][0][0];

#pragma unroll 3
    for (int k = 0; k < 9; ++k) {
        float dy = om0[(2 * k) * 16 + n]     + om1[(2 * k) * 16 + n];
        float dx = om0[(2 * k + 1) * 16 + n] + om1[(2 * k + 1) * 16 + n];
        float mo = om0[(18 + k) * 16 + n]    + om1[(18 + k) * 16 + n];

        b16x8 a0 = wABv[(k * 8 + kh * 4 + 0) * 64 + lane];
        b16x8 a1 = wABv[(k * 8 + kh * 4 + 1) * 64 + lane];
        b16x8 a2 = wABv[(k * 8 + kh * 4 + 2) * 64 + lane];
        b16x8 a3 = wABv[(k * 8 + kh * 4 + 3) * 64 + lane];

        float m  = 1.f / (1.f + __expf(-mo));
        int ky = k / 3, kx = k - ky * 3;
        float ysf = (float)(h0 - 1 + ky) + dy;
        float xsf = (float)(w  - 1 + kx) + dx;
        float y0f = floorf(ysf), x0f = floorf(xsf);
        float ly = ysf - y0f, lx = xsf - x0f;
        float hy = 1.f - ly, hx = 1.f - lx;
        int y0 = (int)y0f, x0 = (int)x0f, y1 = y0 + 1, x1 = x0 + 1;
        bool vy0 = (y0 >= 0) && (y0 < Hs), vy1 = (y1 >= 0) && (y1 < Hs);
        bool vx0 = (x0 >= 0) && (x0 < Ws), vx1 = (x1 >= 0) && (x1 < Ws);
        float W00 = (vy0 && vx0) ? m * hy * hx : 0.f;
        float W01 = (vy0 && vx1) ? m * hy * lx : 0.f;
        float W10 = (vy1 && vx0) ? m * ly * hx : 0.f;
        float W11 = (vy1 && vx1) ? m * ly * lx : 0.f;

        // window membership on UNCLAMPED coords (slot content is clamped data;
        // zero-weight kills out-of-image corners exactly as before)
        bool inw = (y0 >= h0 - 3) && (y1 <= h0 + 3) && (x0 >= c0 - 3) && (x1 <= c0 + 36);

        b16x8 e00, e01, e10, e11;
        if (inw) {
            int sl = (y0 - (h0 - 3)) * WC + (x0 - (c0 - 3));
            e00 = LDSRD(sl);
            e01 = LDSRD(sl + 1);
            e10 = LDSRD(sl + WC);
            e11 = LDSRD(sl + WC + 1);
        } else {   // exact fallback: clamped global gather (rare/never)
            int y0c = min(max(y0, 0), Hs - 1), y1c = min(max(y1, 0), Hs - 1);
            int x0c = min(max(x0, 0), Ws - 1), x1c = min(max(x1, 0), Ws - 1);
            e00 = *(const b16x8*)(xTb + (y0c * Ws + x0c) * 64);
            e01 = *(const b16x8*)(xTb + (y0c * Ws + x1c) * 64);
            e10 = *(const b16x8*)(xTb + (y1c * Ws + x0c) * 64);
            e11 = *(const b16x8*)(xTb + (y1c * Ws + x1c) * 64);
        }

        b16x8 fe;
#pragma unroll
        for (int j = 0; j < 8; ++j)
            fe[j] = (__bf16)((float)e00[j] * W00 + (float)e01[j] * W01 +
                             (float)e10[j] * W10 + (float)e11[j] * W11);

        acc0 = __builtin_amdgcn_mfma_f32_16x16x32_bf16(a0, fe, acc0, 0, 0, 0);
        acc1 = __builtin_amdgcn_mfma_f32_16x16x32_bf16(a1, fe, acc1, 0, 0, 0);
        acc2 = __builtin_amdgcn_mfma_f32_16x16x32_bf16(a2, fe, acc2, 0, 0, 0);
        acc3 = __builtin_amdgcn_mfma_f32_16x16x32_bf16(a3, fe, acc3, 0, 0, 0);
    }
#undef LDSRD

    // ---------------- Epilogue: cross-K-half exchange + store ---------------
    __syncthreads();                       // window dead; reuse as exchange buf
    float* xch = (float*)smemWin;
    {
        f32x4* xw = (f32x4*)&xch[((s * 2 + kh) * 64 + lane) * 8];
        if (kh == 0) { xw[0] = acc2; xw[1] = acc3; }
        else         { xw[0] = acc0; xw[1] = acc1; }
    }
    __syncthreads();
    {
        const f32x4* xr = (const f32x4*)&xch[((s * 2 + (kh ^ 1)) * 64 + lane) * 8];
        f32x4 t0 = xr[0], t1 = xr[1];
        int rr = rblk + s * 16 + n;
        int ob = b * (COUT_ * PLANE) + rr;
        if (kh == 0) {
            f32x4 bs0 = *(const f32x4*)&bias[q * 4];
            f32x4 bs1 = *(const f32x4*)&bias[16 + q * 4];
#pragma unroll
            for (int rg = 0; rg < 4; ++rg) { int o =      q * 4 + rg; out[ob + o * PLANE] = acc0[rg] + t0[rg] + bs0[rg]; }
#pragma unroll
            for (int rg = 0; rg < 4; ++rg) { int o = 16 + q * 4 + rg; out[ob + o * PLANE] = acc1[rg] + t1[rg] + bs1[rg]; }
        } else {
            f32x4 bs2 = *(const f32x4*)&bias[32 + q * 4];
            f32x4 bs3 = *(const f32x4*)&bias[48 + q * 4];
#pragma unroll
            for (int rg = 0; rg < 4; ++rg) { int o = 32 + q * 4 + rg; out[ob + o * PLANE] = acc2[rg] + t0[rg] + bs2[rg]; }
#pragma unroll
            for (int rg = 0; rg < 4; ++rg) { int o = 48 + q * 4 + rg; out[ob + o * PLANE] = acc3[rg] + t1[rg] + bs3[rg]; }
        }
    }
}

extern "C" void kernel_launch(void* const* d_in, const int* in_sizes, int n_in,
                              void* d_out, int out_size, void* d_ws, size_t ws_size,
                              hipStream_t stream) {
    const float* x      = (const float*)d_in[0];
    const float* w_off  = (const float*)d_in[1];
    const float* b_off  = (const float*)d_in[2];
    const float* weight = (const float*)d_in[3];
    const float* bias   = (const float*)d_in[4];
    float* out = (float*)d_out;

    char* ws = (char*)d_ws;
    __bf16* wAB = (__bf16*)ws;               //  73728 B
    __bf16* wAO = (__bf16*)(ws + 73728);     //  36864 B
    __bf16* xT  = (__bf16*)(ws + 131072);    // 9437184 B (bf16 channel-last)

    prep_xpose<<<432, 256, 0, stream>>>(x, weight, w_off, xT, wAB, wAO);
    deform_mfma<<<NBLK, 256, 0, stream>>>(xT, wAO, b_off, wAB, bias, out);
}

// Round 4
// 115.076 us; speedup vs baseline: 1.7582x; 1.0259x over previous
//
#include <hip/hip_runtime.h>
#include <math.h>

typedef __bf16 b16x8 __attribute__((ext_vector_type(8)));
typedef float  f32x4 __attribute__((ext_vector_type(4)));

#define B_    8
#define CIN_  64
#define COUT_ 64
#define Hs    96
#define Ws    96
#define PLANE (Hs*Ws)        // 9216
#define IMG   (CIN_*PLANE)   // 589824
#define NP    (B_*PLANE)     // 73728
#define NBLK  (NP/32)        // 2304 blocks, 32 px each as a 2-row x 16-col tile

// LDS window for a 2x16 tile: rows h0-3..h0+4 (8), cols c0-3..c0+20 (24)
#define WR 8
#define WC 24
#define WPIX (WR*WC)         // 192
#define WBYTES (WPIX*128)    // 24576 B

__device__ __forceinline__ int swz(int bid) { return (bid & 7) * (NBLK / 8) + (bid >> 3); }

// Fused: blocks [0,288) transpose x -> channel-last bf16 xT;
//        blocks [288,432) repack weights into per-lane MFMA A-fragment order.
__global__ void prep_xpose(const float* __restrict__ x,
                           const float* __restrict__ weight, const float* __restrict__ w_off,
                           __bf16* __restrict__ xT,
                           __bf16* __restrict__ wAB, __bf16* __restrict__ wAO) {
    int bid = blockIdx.x;
    if (bid < 288) {
        int p = bid * 256 + threadIdx.x;
        int b = p / PLANE, r = p - b * PLANE;
        const float* src = x + b * IMG + r;
        __bf16 buf[64];
#pragma unroll
        for (int c = 0; c < 64; ++c) buf[c] = (__bf16)src[c * PLANE];
        b16x8* dst = (b16x8*)(xT + (size_t)p * 64);
#pragma unroll
        for (int j = 0; j < 8; ++j) dst[j] = ((const b16x8*)buf)[j];
    } else {
        int i = (bid - 288) * 256 + threadIdx.x;
        if (i < 36864) {
            int e = i & 7, lane = (i >> 3) & 63, mt = (i >> 9) & 3, ks = (i >> 11) & 1, k = i >> 12;
            int o = mt * 16 + (lane & 15);
            int c = ks * 32 + ((lane >> 4) << 3) + e;
            wAB[i] = (__bf16)weight[o * 576 + c * 9 + k];
        }
        if (i < 18432) {
            int e = i & 7, lane = (i >> 3) & 63, mt = (i >> 9) & 1, ks = (i >> 10) & 1, t = i >> 11;
            int ch = mt * 16 + (lane & 15);
            int c  = ks * 32 + ((lane >> 4) << 3) + e;
            wAO[i] = (ch < 27) ? (__bf16)w_off[ch * 576 + c * 9 + t] : (__bf16)(0.f);
        }
    }
}

// R4: 2x16 tile. R3 proved gather-transactions were the wall (LDS window:
// 70.9 -> ~43 us). Remaining budget = LDS instr volume + residency: the 7x40
// window was 35.8 KB -> 3 blocks/CU (37% occ, 3 dispatch rounds) and 280
// staged lines/block. A 2-row x 16-col tile needs only 8x24 = 192 lines
// (24.6 KB): -31% stage traffic, 5 blocks/CU (62% occ), 2 rounds.
// launch_bounds(256,4): VGPR cap 128 (R1 lesson: no tight caps); actual
// ~80-100 so residency is LDS-limited at 5 blocks.
__global__ __launch_bounds__(256, 4)
void deform_mfma(const __bf16* __restrict__ xT,
                 const __bf16* __restrict__ wAO,
                 const float* __restrict__ b_off,
                 const __bf16* __restrict__ wAB,
                 const float* __restrict__ bias,
                 float* __restrict__ out) {
    __shared__ __align__(16) unsigned char smemWin[WBYTES];   // window; aliased by epilogue xch
    __shared__ float omP[2][2][28][16];                        // [strip][khalf][ch][n] 7168 B

    int tid  = threadIdx.x;
    int lane = tid & 63;
    int g    = __builtin_amdgcn_readfirstlane(tid >> 6);
    int s    = g & 1;        // strip = row within 2x16 tile
    int kh   = g >> 1;       // K-half: input channels kh*32..kh*32+31
    int n    = lane & 15;    // pixel col within strip / MFMA col
    int q    = lane >> 4;    // octet: channels kh*32 + q*8 .. +7

    int t    = swz(blockIdx.x);
    int b    = t / 288;            // 288 tiles per image (48 row-pairs x 6 col-tiles)
    int rem  = t - b * 288;
    int rp   = rem / 6;
    int ct   = rem - rp * 6;
    int h0   = rp * 2;             // tile top row
    int c0   = ct * 16;            // tile left col
    int hrow = h0 + s;             // this strip's row
    int w    = c0 + n;             // this lane's col

    const __bf16* xTimg = xT + (size_t)b * PLANE * 64;
    const __bf16* xTb   = xTimg + kh * 32 + q * 8;   // fallback gather base

    const b16x8* wAOv = (const b16x8*)wAO;
    const b16x8* wABv = (const b16x8*)wAB;
    int boff = kh * 64 + q * 16;   // this lane's byte offset within a pixel line

#define LDSRD(sl) (*(const b16x8*)(smemWin + (sl) * 128 + (boff ^ (((sl) & 7) << 4))))

    // ---------------- Stage window: 192 px * 128 B, coalesced ---------------
    // 1536 chunks = 6 exactly per thread. Swizzled write: byte ^= (slot&7)<<4
    // so phase reads (16 lanes, consecutive slots, same boff) spread across 8
    // bank groups (2-way = free).
#pragma unroll
    for (int r2 = 0; r2 < 6; ++r2) {
        int idx = tid + r2 * 256;
        int pix = idx >> 3, j = idx & 7;
        int yw = pix / WC, xw = pix - yw * WC;
        int ys = min(max(h0 - 3 + yw, 0), Hs - 1);
        int xs = min(max(c0 - 3 + xw, 0), Ws - 1);
        b16x8 v = *(const b16x8*)(xTimg + ((ys * Ws + xs) * 64) + j * 8);
        *(b16x8*)(smemWin + pix * 128 + ((j * 16) ^ ((pix & 7) << 4))) = v;
    }
    __syncthreads();

    // ---------------- Phase A: offset conv via MFMA (K-half partial) --------
    // Taps sample (hrow-1+ky, w-1+kx): rows h0-1..h0+2, cols c0-1..c0+16 --
    // always inside the window.
    f32x4 accA0 = {0.f, 0.f, 0.f, 0.f};
    f32x4 accA1 = {0.f, 0.f, 0.f, 0.f};
    const b16x8 ZER = {};

#pragma unroll 3
    for (int tt = 0; tt < 9; ++tt) {
        int ky = tt / 3, kx = tt - ky * 3;
        int yy = hrow - 1 + ky, xx = w - 1 + kx;
        bool mk = (yy >= 0 && yy < Hs && xx >= 0 && xx < Ws);   // zero-pad conv
        int sl = (s + 2 + ky) * WC + (n + 2 + kx);
        b16x8 bf = LDSRD(sl);
        bf = mk ? bf : ZER;
        b16x8 af0 = wAOv[((tt * 2 + kh) * 2 + 0) * 64 + lane];
        b16x8 af1 = wAOv[((tt * 2 + kh) * 2 + 1) * 64 + lane];
        accA0 = __builtin_amdgcn_mfma_f32_16x16x32_bf16(af0, bf, accA0, 0, 0, 0);
        accA1 = __builtin_amdgcn_mfma_f32_16x16x32_bf16(af1, bf, accA1, 0, 0, 0);
    }
#pragma unroll
    for (int rg = 0; rg < 4; ++rg) {
        int ch = q * 4 + rg;
        omP[s][kh][ch][n] = accA0[rg] + (kh ? 0.f : b_off[ch]);
    }
#pragma unroll
    for (int rg = 0; rg < 4; ++rg) {
        int ch = 16 + q * 4 + rg;
        if (ch < 27) omP[s][kh][ch][n] = accA1[rg] + (kh ? 0.f : b_off[ch]);
    }
    __syncthreads();

    // ---------------- Phase B: sampling (from LDS) + main conv --------------
    f32x4 acc0 = {0.f, 0.f, 0.f, 0.f};
    f32x4 acc1 = {0.f, 0.f, 0.f, 0.f};
    f32x4 acc2 = {0.f, 0.f, 0.f, 0.f};
    f32x4 acc3 = {0.f, 0.f, 0.f, 0.f};

    const float* om0 = &omP[s][0][0][0];
    const float* om1 = &omP[s][1][0][0];

#pragma unroll 3
    for (int k = 0; k < 9; ++k) {
        float dy = om0[(2 * k) * 16 + n]     + om1[(2 * k) * 16 + n];
        float dx = om0[(2 * k + 1) * 16 + n] + om1[(2 * k + 1) * 16 + n];
        float mo = om0[(18 + k) * 16 + n]    + om1[(18 + k) * 16 + n];

        b16x8 a0 = wABv[(k * 8 + kh * 4 + 0) * 64 + lane];
        b16x8 a1 = wABv[(k * 8 + kh * 4 + 1) * 64 + lane];
        b16x8 a2 = wABv[(k * 8 + kh * 4 + 2) * 64 + lane];
        b16x8 a3 = wABv[(k * 8 + kh * 4 + 3) * 64 + lane];

        float m  = 1.f / (1.f + __expf(-mo));
        int ky = k / 3, kx = k - ky * 3;
        float ysf = (float)(hrow - 1 + ky) + dy;
        float xsf = (float)(w    - 1 + kx) + dx;
        float y0f = floorf(ysf), x0f = floorf(xsf);
        float ly = ysf - y0f, lx = xsf - x0f;
        float hy = 1.f - ly, hx = 1.f - lx;
        int y0 = (int)y0f, x0 = (int)x0f, y1 = y0 + 1, x1 = x0 + 1;
        bool vy0 = (y0 >= 0) && (y0 < Hs), vy1 = (y1 >= 0) && (y1 < Hs);
        bool vx0 = (x0 >= 0) && (x0 < Ws), vx1 = (x1 >= 0) && (x1 < Ws);
        float W00 = (vy0 && vx0) ? m * hy * hx : 0.f;
        float W01 = (vy0 && vx1) ? m * hy * lx : 0.f;
        float W10 = (vy1 && vx0) ? m * ly * hx : 0.f;
        float W11 = (vy1 && vx1) ? m * ly * lx : 0.f;

        // window membership on UNCLAMPED coords (slot content is clamped data;
        // zero-weight kills out-of-image corners exactly as before)
        bool inw = (y0 >= h0 - 3) && (y1 <= h0 + 4) && (x0 >= c0 - 3) && (x1 <= c0 + 20);

        b16x8 e00, e01, e10, e11;
        if (inw) {
            int sl = (y0 - (h0 - 3)) * WC + (x0 - (c0 - 3));
            e00 = LDSRD(sl);
            e01 = LDSRD(sl + 1);
            e10 = LDSRD(sl + WC);
            e11 = LDSRD(sl + WC + 1);
        } else {   // exact fallback: clamped global gather (rare/never)
            int y0c = min(max(y0, 0), Hs - 1), y1c = min(max(y1, 0), Hs - 1);
            int x0c = min(max(x0, 0), Ws - 1), x1c = min(max(x1, 0), Ws - 1);
            e00 = *(const b16x8*)(xTb + (y0c * Ws + x0c) * 64);
            e01 = *(const b16x8*)(xTb + (y0c * Ws + x1c) * 64);
            e10 = *(const b16x8*)(xTb + (y1c * Ws + x0c) * 64);
            e11 = *(const b16x8*)(xTb + (y1c * Ws + x1c) * 64);
        }

        b16x8 fe;
#pragma unroll
        for (int j = 0; j < 8; ++j)
            fe[j] = (__bf16)((float)e00[j] * W00 + (float)e01[j] * W01 +
                             (float)e10[j] * W10 + (float)e11[j] * W11);

        acc0 = __builtin_amdgcn_mfma_f32_16x16x32_bf16(a0, fe, acc0, 0, 0, 0);
        acc1 = __builtin_amdgcn_mfma_f32_16x16x32_bf16(a1, fe, acc1, 0, 0, 0);
        acc2 = __builtin_amdgcn_mfma_f32_16x16x32_bf16(a2, fe, acc2, 0, 0, 0);
        acc3 = __builtin_amdgcn_mfma_f32_16x16x32_bf16(a3, fe, acc3, 0, 0, 0);
    }
#undef LDSRD

    // ---------------- Epilogue: cross-K-half exchange + store ---------------
    __syncthreads();                       // window dead; reuse as exchange buf
    float* xch = (float*)smemWin;
    {
        f32x4* xw = (f32x4*)&xch[((s * 2 + kh) * 64 + lane) * 8];
        if (kh == 0) { xw[0] = acc2; xw[1] = acc3; }
        else         { xw[0] = acc0; xw[1] = acc1; }
    }
    __syncthreads();
    {
        const f32x4* xr = (const f32x4*)&xch[((s * 2 + (kh ^ 1)) * 64 + lane) * 8];
        f32x4 t0 = xr[0], t1 = xr[1];
        int rr = hrow * Ws + w;
        int ob = b * (COUT_ * PLANE) + rr;
        if (kh == 0) {
            f32x4 bs0 = *(const f32x4*)&bias[q * 4];
            f32x4 bs1 = *(const f32x4*)&bias[16 + q * 4];
#pragma unroll
            for (int rg = 0; rg < 4; ++rg) { int o =      q * 4 + rg; out[ob + o * PLANE] = acc0[rg] + t0[rg] + bs0[rg]; }
#pragma unroll
            for (int rg = 0; rg < 4; ++rg) { int o = 16 + q * 4 + rg; out[ob + o * PLANE] = acc1[rg] + t1[rg] + bs1[rg]; }
        } else {
            f32x4 bs2 = *(const f32x4*)&bias[32 + q * 4];
            f32x4 bs3 = *(const f32x4*)&bias[48 + q * 4];
#pragma unroll
            for (int rg = 0; rg < 4; ++rg) { int o = 32 + q * 4 + rg; out[ob + o * PLANE] = acc2[rg] + t0[rg] + bs2[rg]; }
#pragma unroll
            for (int rg = 0; rg < 4; ++rg) { int o = 48 + q * 4 + rg; out[ob + o * PLANE] = acc3[rg] + t1[rg] + bs3[rg]; }
        }
    }
}

extern "C" void kernel_launch(void* const* d_in, const int* in_sizes, int n_in,
                              void* d_out, int out_size, void* d_ws, size_t ws_size,
                              hipStream_t stream) {
    const float* x      = (const float*)d_in[0];
    const float* w_off  = (const float*)d_in[1];
    const float* b_off  = (const float*)d_in[2];
    const float* weight = (const float*)d_in[3];
    const float* bias   = (const float*)d_in[4];
    float* out = (float*)d_out;

    char* ws = (char*)d_ws;
    __bf16* wAB = (__bf16*)ws;               //  73728 B
    __bf16* wAO = (__bf16*)(ws + 73728);     //  36864 B
    __bf16* xT  = (__bf16*)(ws + 131072);    // 9437184 B (bf16 channel-last)

    prep_xpose<<<432, 256, 0, stream>>>(x, weight, w_off, xT, wAB, wAO);
    deform_mfma<<<NBLK, 256, 0, stream>>>(xT, wAO, b_off, wAB, bias, out);
}